// Round 4
// baseline (843.216 us; speedup 1.0000x reference)
//
#include <hip/hip_runtime.h>

// ManifoldHyperConnections, R8.
// R7 (no-LDS + 256 big inline-asm s_load blocks) core-dumped; R6 (LDS x +
// asm s_load w) passed at 162us. R8 keeps R7's architecture -- no LDS, no
// barriers, lane owns one row, w on the scalar pipe -- but drops ALL inline
// asm: the w address is uniform by construction (blockIdx + compile-time
// offsets) and w is a const __restrict__ arg, so the backend's
// uniform+noclobber analysis emits s_load_dwordx8/x16 itself.
// x: global->VGPR direct, 1 x 128B line per lane per 32-k step, A/B
// double-buffered so the next step's 8 dwordx4 stay in flight under the
// current step's ~1200 FMA cycles.
// KC=64 (1024 blocks): 4 waves/SIMD residency (R6/R7 had only 2).
// Partials: [kc][j][row] plain coalesced stores, no atomics, no memset.
// Epilogue: reduce 64 chunks (unroll 4 -> ~100 loads in flight) + Sinkhorn
// with bitwise fixed-point early exit (exact-output preserving).

typedef float f4 __attribute__((ext_vector_type(4)));

#define TROWS 4096
#define KDIM  16384
#define NOUT  24
#define KC    64                   // split-K chunks
#define KPER  (KDIM / KC)          // 256 k per chunk
#define NSTEP (KPER / 32)          // 8 outer steps of 32 k (one 128B line)
#define NSLOT 25

__device__ __forceinline__ float fast_rcp(float x)   { return __builtin_amdgcn_rcpf(x); }
__device__ __forceinline__ float fast_rsqrt(float x) { return __builtin_amdgcn_rsqf(x); }

__global__ __launch_bounds__(256, 4) void gemv_part(const float* __restrict__ x,
                                                    const float* __restrict__ w,
                                                    float* __restrict__ hacc) {
    const int bid = blockIdx.x;
    const int rb  = bid & 15;          // row block 0..15 (256 rows each)
    const int kc  = bid >> 4;          // split-K chunk 0..63
    const int t   = threadIdx.x;
    const int row = rb * 256 + t;      // lane owns this row
    const int k0  = kc * KPER;

    float acc[NOUT];
    float ss = 0.0f;
#pragma unroll
    for (int j = 0; j < NOUT; ++j) acc[j] = 0.0f;

    const float* xg = x + (size_t)row * KDIM + k0;

    f4 A[8], B[8];

    // Load 8 x float4 (one 128B line) for this lane's row, step i.
#define ISSUE(BUF, i)                                                      \
    {                                                                      \
        const float* b_ = xg + 32 * (i);                                   \
        _Pragma("unroll")                                                  \
        for (int j_ = 0; j_ < 8; ++j_) BUF[j_] = *(const f4*)(b_ + 4 * j_);\
    }

    // Consume BUF (32 k) against w rows k0+32i .. k0+32i+31 (uniform addr;
    // backend emits s_load -- scalar pipe, zero VALU/LDS cost).
#define COMPUTE(BUF, i)                                                    \
    {                                                                      \
        const float* wk_ = w + (size_t)(k0 + 32 * (i)) * NOUT;             \
        _Pragma("unroll")                                                  \
        for (int h_ = 0; h_ < 16; ++h_) {                                  \
            const float* wr_ = wk_ + h_ * (2 * NOUT);                      \
            const f4 v_ = BUF[h_ >> 1];                                    \
            const float c0_ = (h_ & 1) ? v_.z : v_.x;                      \
            const float c1_ = (h_ & 1) ? v_.w : v_.y;                      \
            ss = fmaf(c0_, c0_, ss);                                       \
            ss = fmaf(c1_, c1_, ss);                                       \
            _Pragma("unroll")                                              \
            for (int m_ = 0; m_ < NOUT; ++m_) {                            \
                acc[m_] = fmaf(wr_[m_], c0_, acc[m_]);                     \
                acc[m_] = fmaf(wr_[NOUT + m_], c1_, acc[m_]);              \
            }                                                              \
        }                                                                  \
    }

    ISSUE(A, 0)
#pragma unroll 1
    for (int p = 0; p < NSTEP / 2; ++p) {
        ISSUE(B, 2 * p + 1)                       // in flight under COMPUTE(A)
        COMPUTE(A, 2 * p)
        if (p < NSTEP / 2 - 1) ISSUE(A, 2 * p + 2)  // in flight under COMPUTE(B)
        COMPUTE(B, 2 * p + 1)
    }
#undef ISSUE
#undef COMPUTE

    // plain coalesced stores: hacc[kc][j][row], consecutive lanes -> rows
    float* hb = hacc + (size_t)kc * NSLOT * TROWS + row;
#pragma unroll
    for (int j = 0; j < NOUT; ++j) hb[(size_t)j * TROWS] = acc[j];
    hb[(size_t)NOUT * TROWS] = ss;
}

__global__ __launch_bounds__(64) void sinkhorn_epilogue(const float* __restrict__ hacc,
                                                        const float* __restrict__ bias,
                                                        const float* __restrict__ alpha,
                                                        float* __restrict__ out) {
    const int row = blockIdx.x * 64 + threadIdx.x;

    // reduce the 64 split-K chunks (coalesced: lane == row)
    float h[25];
#pragma unroll
    for (int j = 0; j < 25; ++j) h[j] = 0.0f;
#pragma unroll 4
    for (int c = 0; c < KC; ++c) {
        const float* hp = hacc + (size_t)c * NSLOT * TROWS + row;
#pragma unroll
        for (int j = 0; j < 25; ++j) h[j] += hp[(size_t)j * TROWS];
    }

    const float r_inv = fast_rsqrt(h[24] * (1.0f / (float)KDIM));
    const float a0 = alpha[0], a1 = alpha[1], a2 = alpha[2];

#pragma unroll
    for (int i = 0; i < 4; ++i) {
        const float zpre = fmaf(r_inv * a0, h[i], bias[i]);
        out[(size_t)row * 4 + i] = fast_rcp(1.0f + __expf(-zpre));
        const float zpo = fmaf(r_inv * a1, h[4 + i], bias[4 + i]);
        out[(size_t)16384 + (size_t)row * 4 + i] = 2.0f * fast_rcp(1.0f + __expf(-zpo));
    }

    float E[16];
#pragma unroll
    for (int q = 0; q < 16; ++q)
        E[q] = __expf(fmaf(r_inv * a2, h[8 + q], bias[8 + q]));

    float u0 = 1.0f, u1 = 1.0f, u2 = 1.0f, u3 = 1.0f;
    float v0 = 1.0f, v1 = 1.0f, v2 = 1.0f, v3 = 1.0f;
    float pu0 = 1.0f, pu1 = 1.0f, pu2 = 1.0f, pu3 = 1.0f;
    float pv0 = 1.0f, pv1 = 1.0f, pv2 = 1.0f, pv3 = 1.0f;

    // Bitwise fixed-point early exit: once (u,v) repeats exactly, all
    // remaining iterations are identity -> exact output. Falls back to
    // the full 400 if it never triggers.
#pragma unroll 1
    for (int it = 0; it < 400; ++it) {
        float s0 = fmaf(E[0],  v0, E[1]  * v1) + fmaf(E[2],  v2, E[3]  * v3);
        float s1 = fmaf(E[4],  v0, E[5]  * v1) + fmaf(E[6],  v2, E[7]  * v3);
        float s2 = fmaf(E[8],  v0, E[9]  * v1) + fmaf(E[10], v2, E[11] * v3);
        float s3 = fmaf(E[12], v0, E[13] * v1) + fmaf(E[14], v2, E[15] * v3);
        u0 = fast_rcp(s0 + 1e-12f);
        u1 = fast_rcp(s1 + 1e-12f);
        u2 = fast_rcp(s2 + 1e-12f);
        u3 = fast_rcp(s3 + 1e-12f);
        float t0 = fmaf(E[0], u0, E[4]  * u1) + fmaf(E[8],  u2, E[12] * u3);
        float t1 = fmaf(E[1], u0, E[5]  * u1) + fmaf(E[9],  u2, E[13] * u3);
        float t2 = fmaf(E[2], u0, E[6]  * u1) + fmaf(E[10], u2, E[14] * u3);
        float t3 = fmaf(E[3], u0, E[7]  * u1) + fmaf(E[11], u2, E[15] * u3);
        v0 = fast_rcp(t0 + 1e-12f);
        v1 = fast_rcp(t1 + 1e-12f);
        v2 = fast_rcp(t2 + 1e-12f);
        v3 = fast_rcp(t3 + 1e-12f);

        const int conv = (u0 == pu0) & (u1 == pu1) & (u2 == pu2) & (u3 == pu3)
                       & (v0 == pv0) & (v1 == pv1) & (v2 == pv2) & (v3 == pv3);
        pu0 = u0; pu1 = u1; pu2 = u2; pu3 = u3;
        pv0 = v0; pv1 = v1; pv2 = v2; pv3 = v3;
        if (__all(conv)) break;
    }

    const size_t ob = 32768 + (size_t)row * 16;
    out[ob + 0]  = u0 * E[0]  * v0;
    out[ob + 1]  = u0 * E[1]  * v1;
    out[ob + 2]  = u0 * E[2]  * v2;
    out[ob + 3]  = u0 * E[3]  * v3;
    out[ob + 4]  = u1 * E[4]  * v0;
    out[ob + 5]  = u1 * E[5]  * v1;
    out[ob + 6]  = u1 * E[6]  * v2;
    out[ob + 7]  = u1 * E[7]  * v3;
    out[ob + 8]  = u2 * E[8]  * v0;
    out[ob + 9]  = u2 * E[9]  * v1;
    out[ob + 10] = u2 * E[10] * v2;
    out[ob + 11] = u2 * E[11] * v3;
    out[ob + 12] = u3 * E[12] * v0;
    out[ob + 13] = u3 * E[13] * v1;
    out[ob + 14] = u3 * E[14] * v2;
    out[ob + 15] = u3 * E[15] * v3;
}

extern "C" void kernel_launch(void* const* d_in, const int* in_sizes, int n_in,
                              void* d_out, int out_size, void* d_ws, size_t ws_size,
                              hipStream_t stream) {
    const float* x     = (const float*)d_in[0];
    const float* w     = (const float*)d_in[1];
    const float* bias  = (const float*)d_in[2];
    const float* alpha = (const float*)d_in[3];
    float* out  = (float*)d_out;
    float* hacc = (float*)d_ws;   // KC * 25 * 4096 floats = 26.2 MB

    // no memset: every hacc slot is written unconditionally by gemv_part
    gemv_part<<<dim3(16 * KC), dim3(256), 0, stream>>>(x, w, hacc);
    sinkhorn_epilogue<<<dim3(TROWS / 64), dim3(64), 0, stream>>>(hacc, bias, alpha, out);
}

// Round 6
// 803.156 us; speedup vs baseline: 1.0499x; 1.0499x over previous
//
#include <hip/hip_runtime.h>

// ManifoldHyperConnections, R10.
// Crash forensics: R6 (1 asm site) and R8 (no asm) pass; R7/R9 (replicated
// 48-SGPR asm macro) core-dump -> in-process compile ICE. Inline asm is
// retired. R10 gets scalar-pipe w WITHOUT asm: readfirstlane the w pointer
// (result is uniform by definition) and load through an
// __attribute__((address_space(4))) ("constant") pointer -- uniform
// constant-addrspace loads lower to s_load_dwordx4, are invariant (compiler
// clusters/hoists them and manages lgkmcnt), and stay OFF the vmcnt queue,
// so the x A/B double-buffer actually overlaps (R8's failure mode).
// Architecture unchanged from R8 (passed): no LDS, no barriers, lane owns
// one row, KC=64 -> 1024 blocks = 4 waves/SIMD, plain coalesced partial
// stores [kc][j][row], no atomics, no memset. Epilogue: reduce 64 chunks +
// Sinkhorn with bitwise fixed-point early exit (exact-output preserving).

typedef float f4 __attribute__((ext_vector_type(4)));
typedef const __attribute__((address_space(4))) f4* sf4p;

#define TROWS 4096
#define KDIM  16384
#define NOUT  24
#define KC    64                   // split-K chunks
#define KPER  (KDIM / KC)          // 256 k per chunk
#define NSTEP (KPER / 32)          // 8 outer steps of 32 k
#define NSLOT 25

__device__ __forceinline__ float fast_rcp(float x)   { return __builtin_amdgcn_rcpf(x); }
__device__ __forceinline__ float fast_rsqrt(float x) { return __builtin_amdgcn_rsqf(x); }

// Wave-uniform scalar pointer: readfirstlane both halves (backend-uniform),
// reinterpret as constant-addrspace f4*. Dereferences become s_load_dwordx4.
__device__ __forceinline__ sf4p scalar_f4_ptr(const float* p) {
    const unsigned long long v = (unsigned long long)p;
    const unsigned int lo = __builtin_amdgcn_readfirstlane((unsigned int)v);
    const unsigned int hi = __builtin_amdgcn_readfirstlane((unsigned int)(v >> 32));
    return (sf4p)(((unsigned long long)hi << 32) | lo);
}

__global__ __launch_bounds__(256, 4) void gemv_part(const float* __restrict__ x,
                                                    const float* __restrict__ w,
                                                    float* __restrict__ hacc) {
    const int bid = blockIdx.x;
    const int rb  = bid & 15;          // row block 0..15 (256 rows each)
    const int kc  = bid >> 4;          // split-K chunk 0..63
    const int t   = threadIdx.x;
    const int row = rb * 256 + t;      // lane owns this row
    const int k0  = kc * KPER;

    float acc[NOUT];
    float ss = 0.0f;
#pragma unroll
    for (int j = 0; j < NOUT; ++j) acc[j] = 0.0f;

    const float* xg = x + (size_t)row * KDIM + k0;

    f4 A[8], B[8];

    // Load 8 x float4 (one 128B line) for this lane's row, step i.
#define ISSUE(BUF, i)                                                      \
    {                                                                      \
        const float* b_ = xg + 32 * (i);                                   \
        _Pragma("unroll")                                                  \
        for (int j_ = 0; j_ < 8; ++j_) BUF[j_] = *(const f4*)(b_ + 4 * j_);\
    }

    // Consume BUF (32 k) against w rows k0+32i..+31 via the SCALAR pipe:
    // wk is a uniform constant-addrspace pointer -> s_load_dwordx4 per f4.
#define COMPUTE(BUF, i)                                                    \
    {                                                                      \
        sf4p wk_ = scalar_f4_ptr(w + (size_t)(k0 + 32 * (i)) * NOUT);      \
        _Pragma("unroll")                                                  \
        for (int h_ = 0; h_ < 16; ++h_) {                                  \
            float w0_[NOUT], w1_[NOUT];                                    \
            _Pragma("unroll")                                              \
            for (int q_ = 0; q_ < 6; ++q_)                                 \
                *(f4*)(w0_ + 4 * q_) = wk_[h_ * 12 + q_];                  \
            _Pragma("unroll")                                              \
            for (int q_ = 0; q_ < 6; ++q_)                                 \
                *(f4*)(w1_ + 4 * q_) = wk_[h_ * 12 + 6 + q_];              \
            const f4 v_ = BUF[h_ >> 1];                                    \
            const float c0_ = (h_ & 1) ? v_.z : v_.x;                      \
            const float c1_ = (h_ & 1) ? v_.w : v_.y;                      \
            ss = fmaf(c0_, c0_, ss);                                       \
            ss = fmaf(c1_, c1_, ss);                                       \
            _Pragma("unroll")                                              \
            for (int m_ = 0; m_ < NOUT; ++m_) {                            \
                acc[m_] = fmaf(w0_[m_], c0_, acc[m_]);                     \
                acc[m_] = fmaf(w1_[m_], c1_, acc[m_]);                     \
            }                                                              \
        }                                                                  \
    }

    ISSUE(A, 0)
#pragma unroll 1
    for (int p = 0; p < NSTEP / 2; ++p) {
        ISSUE(B, 2 * p + 1)                          // in flight under COMPUTE(A)
        COMPUTE(A, 2 * p)
        if (p < NSTEP / 2 - 1) ISSUE(A, 2 * p + 2)   // in flight under COMPUTE(B)
        COMPUTE(B, 2 * p + 1)
    }
#undef ISSUE
#undef COMPUTE

    // plain coalesced stores: hacc[kc][j][row], consecutive lanes -> rows
    float* hb = hacc + (size_t)kc * NSLOT * TROWS + row;
#pragma unroll
    for (int j = 0; j < NOUT; ++j) hb[(size_t)j * TROWS] = acc[j];
    hb[(size_t)NOUT * TROWS] = ss;
}

__global__ __launch_bounds__(64) void sinkhorn_epilogue(const float* __restrict__ hacc,
                                                        const float* __restrict__ bias,
                                                        const float* __restrict__ alpha,
                                                        float* __restrict__ out) {
    const int row = blockIdx.x * 64 + threadIdx.x;

    // reduce the 64 split-K chunks (coalesced: lane == row)
    float h[25];
#pragma unroll
    for (int j = 0; j < 25; ++j) h[j] = 0.0f;
#pragma unroll 4
    for (int c = 0; c < KC; ++c) {
        const float* hp = hacc + (size_t)c * NSLOT * TROWS + row;
#pragma unroll
        for (int j = 0; j < 25; ++j) h[j] += hp[(size_t)j * TROWS];
    }

    const float r_inv = fast_rsqrt(h[24] * (1.0f / (float)KDIM));
    const float a0 = alpha[0], a1 = alpha[1], a2 = alpha[2];

#pragma unroll
    for (int i = 0; i < 4; ++i) {
        const float zpre = fmaf(r_inv * a0, h[i], bias[i]);
        out[(size_t)row * 4 + i] = fast_rcp(1.0f + __expf(-zpre));
        const float zpo = fmaf(r_inv * a1, h[4 + i], bias[4 + i]);
        out[(size_t)16384 + (size_t)row * 4 + i] = 2.0f * fast_rcp(1.0f + __expf(-zpo));
    }

    float E[16];
#pragma unroll
    for (int q = 0; q < 16; ++q)
        E[q] = __expf(fmaf(r_inv * a2, h[8 + q], bias[8 + q]));

    float u0 = 1.0f, u1 = 1.0f, u2 = 1.0f, u3 = 1.0f;
    float v0 = 1.0f, v1 = 1.0f, v2 = 1.0f, v3 = 1.0f;
    float pu0 = 1.0f, pu1 = 1.0f, pu2 = 1.0f, pu3 = 1.0f;
    float pv0 = 1.0f, pv1 = 1.0f, pv2 = 1.0f, pv3 = 1.0f;

    // Bitwise fixed-point early exit: once (u,v) repeats exactly, all
    // remaining iterations are identity -> exact output. Falls back to
    // the full 400 if it never triggers.
#pragma unroll 1
    for (int it = 0; it < 400; ++it) {
        float s0 = fmaf(E[0],  v0, E[1]  * v1) + fmaf(E[2],  v2, E[3]  * v3);
        float s1 = fmaf(E[4],  v0, E[5]  * v1) + fmaf(E[6],  v2, E[7]  * v3);
        float s2 = fmaf(E[8],  v0, E[9]  * v1) + fmaf(E[10], v2, E[11] * v3);
        float s3 = fmaf(E[12], v0, E[13] * v1) + fmaf(E[14], v2, E[15] * v3);
        u0 = fast_rcp(s0 + 1e-12f);
        u1 = fast_rcp(s1 + 1e-12f);
        u2 = fast_rcp(s2 + 1e-12f);
        u3 = fast_rcp(s3 + 1e-12f);
        float t0 = fmaf(E[0], u0, E[4]  * u1) + fmaf(E[8],  u2, E[12] * u3);
        float t1 = fmaf(E[1], u0, E[5]  * u1) + fmaf(E[9],  u2, E[13] * u3);
        float t2 = fmaf(E[2], u0, E[6]  * u1) + fmaf(E[10], u2, E[14] * u3);
        float t3 = fmaf(E[3], u0, E[7]  * u1) + fmaf(E[11], u2, E[15] * u3);
        v0 = fast_rcp(t0 + 1e-12f);
        v1 = fast_rcp(t1 + 1e-12f);
        v2 = fast_rcp(t2 + 1e-12f);
        v3 = fast_rcp(t3 + 1e-12f);

        const int conv = (u0 == pu0) & (u1 == pu1) & (u2 == pu2) & (u3 == pu3)
                       & (v0 == pv0) & (v1 == pv1) & (v2 == pv2) & (v3 == pv3);
        pu0 = u0; pu1 = u1; pu2 = u2; pu3 = u3;
        pv0 = v0; pv1 = v1; pv2 = v2; pv3 = v3;
        if (__all(conv)) break;
    }

    const size_t ob = 32768 + (size_t)row * 16;
    out[ob + 0]  = u0 * E[0]  * v0;
    out[ob + 1]  = u0 * E[1]  * v1;
    out[ob + 2]  = u0 * E[2]  * v2;
    out[ob + 3]  = u0 * E[3]  * v3;
    out[ob + 4]  = u1 * E[4]  * v0;
    out[ob + 5]  = u1 * E[5]  * v1;
    out[ob + 6]  = u1 * E[6]  * v2;
    out[ob + 7]  = u1 * E[7]  * v3;
    out[ob + 8]  = u2 * E[8]  * v0;
    out[ob + 9]  = u2 * E[9]  * v1;
    out[ob + 10] = u2 * E[10] * v2;
    out[ob + 11] = u2 * E[11] * v3;
    out[ob + 12] = u3 * E[12] * v0;
    out[ob + 13] = u3 * E[13] * v1;
    out[ob + 14] = u3 * E[14] * v2;
    out[ob + 15] = u3 * E[15] * v3;
}

extern "C" void kernel_launch(void* const* d_in, const int* in_sizes, int n_in,
                              void* d_out, int out_size, void* d_ws, size_t ws_size,
                              hipStream_t stream) {
    const float* x     = (const float*)d_in[0];
    const float* w     = (const float*)d_in[1];
    const float* bias  = (const float*)d_in[2];
    const float* alpha = (const float*)d_in[3];
    float* out  = (float*)d_out;
    float* hacc = (float*)d_ws;   // KC * 25 * 4096 floats = 26.2 MB

    // no memset: every hacc slot is written unconditionally by gemv_part
    gemv_part<<<dim3(16 * KC), dim3(256), 0, stream>>>(x, w, hacc);
    sinkhorn_epilogue<<<dim3(TROWS / 64), dim3(64), 0, stream>>>(hacc, bias, alpha, out);
}

// Round 8
// 470.460 us; speedup vs baseline: 1.7923x; 1.7072x over previous
//
#include <hip/hip_runtime.h>

// ManifoldHyperConnections, R12 (= R11 with the compile error fixed:
// split_pair returns uint2 by value; ext_vector elements can't bind to
// non-const references).
// GEMM on MATRIX CORES with split-bf16 (x = hi + lo truncated bf16 pair;
// 3 MFMA passes hi*hi + lo*hi + hi*lo into one fp32 acc -> rel err ~2^-16,
// tolerance is 2^-8). MFMA work ~2us chip-wide; kernel is HBM-bound on x
// (43us floor). A-frags load DIRECTLY from global in fragment order
// (wave = 16 rows x 128B contiguous, fully consumed; no LDS, no barriers).
// W pre-converted once into zero-padded B-frags (2MB, L2). Sumsq rides in
// fp32 + shfl_xor reduce. Epilogue: parallel chunk reduce (~5us) + lean
// Sinkhorn (unroll 1, no spills) with bitwise fixed-point early exit.

typedef float  f4    __attribute__((ext_vector_type(4)));
typedef unsigned int u32x4 __attribute__((ext_vector_type(4)));
typedef short  bf16x8 __attribute__((ext_vector_type(8)));

#define TROWS 4096
#define KDIM  16384
#define NOUT  24
#define KC    64                    // split-K chunks
#define KPER  (KDIM / KC)           // 256 k per chunk
#define NKB   (KPER / 32)           // 8 k-blocks of 32 per chunk
#define NSLOT 25
#define NKBG  (KDIM / 32)           // 512 global k-blocks
#define HACCF ((size_t)KC * NSLOT * TROWS)

__device__ __forceinline__ float fast_rcp(float x)   { return __builtin_amdgcn_rcpf(x); }
__device__ __forceinline__ float fast_rsqrt(float x) { return __builtin_amdgcn_rsqf(x); }

union BU { u32x4 u; bf16x8 b; };
__device__ __forceinline__ bf16x8 as_bf16x8(u32x4 v) { BU t; t.u = v; return t.b; }

// Truncating split: hi = top-16-bits bf16 of f, lo = bf16 of exact residual.
// Returns {hi_packed, lo_packed}: bf16(f0) in low half, bf16(f1) in high.
__device__ __forceinline__ uint2 split_pair(float f0, float f1) {
    const unsigned int b0 = __float_as_uint(f0), b1 = __float_as_uint(f1);
    const unsigned int h0 = b0 & 0xFFFF0000u,    h1 = b1 & 0xFFFF0000u;
    const float r0 = f0 - __uint_as_float(h0);   // exact
    const float r1 = f1 - __uint_as_float(h1);   // exact
    uint2 r;
    r.x = (b0 >> 16) | h1;
    r.y = (__float_as_uint(r0) >> 16) | (__float_as_uint(r1) & 0xFFFF0000u);
    return r;
}

// ---- W -> zero-padded B-fragments (once; 2MB, L2-resident) ----
// frag index = (kbg*2 + tile)*64 + lane; lane holds col = (lane&15)+16*tile,
// k = kbg*32 + (lane>>4)*8 + [0..7], packed as ascending-k bf16 pairs.
__global__ __launch_bounds__(256) void make_wfrags(const float* __restrict__ w,
                                                   u32x4* __restrict__ whi,
                                                   u32x4* __restrict__ wlo) {
    const int idx  = blockIdx.x * 256 + threadIdx.x;   // 0..65535
    const int lane = idx & 63;
    const int tile = (idx >> 6) & 1;
    const int kbg  = idx >> 7;
    const int col  = (lane & 15) + tile * 16;
    const int k0   = kbg * 32 + (lane >> 4) * 8;

    float v[8];
#pragma unroll
    for (int j = 0; j < 8; ++j)
        v[j] = (col < NOUT) ? w[(size_t)(k0 + j) * NOUT + col] : 0.0f;

    u32x4 hi, lo;
    uint2 p0 = split_pair(v[0], v[1]);
    uint2 p1 = split_pair(v[2], v[3]);
    uint2 p2 = split_pair(v[4], v[5]);
    uint2 p3 = split_pair(v[6], v[7]);
    hi.x = p0.x; lo.x = p0.y;
    hi.y = p1.x; lo.y = p1.y;
    hi.z = p2.x; lo.z = p2.y;
    hi.w = p3.x; lo.w = p3.y;
    whi[idx] = hi;
    wlo[idx] = lo;
}

// ---- GEMM partials via MFMA ----
__global__ __launch_bounds__(256, 4) void gemv_mfma(const float* __restrict__ x,
                                                    const u32x4* __restrict__ whi,
                                                    const u32x4* __restrict__ wlo,
                                                    float* __restrict__ hacc) {
    const int bid  = blockIdx.x;
    const int rb   = bid & 15;         // row block (256 rows)
    const int kc   = bid >> 4;         // split-K chunk 0..63
    const int t    = threadIdx.x;
    const int wv   = t >> 6;           // wave 0..3 -> 64 rows
    const int lane = t & 63;
    const int l15  = lane & 15;
    const int lg   = lane >> 4;        // k-group 0..3

    const int rowbase = rb * 256 + wv * 64;

    f4 acc[4][2];                      // [m-tile][n-tile], fp32 C frags
#pragma unroll
    for (int m = 0; m < 4; ++m) { acc[m][0] = (f4)0.0f; acc[m][1] = (f4)0.0f; }
    float ss[4] = {0.0f, 0.0f, 0.0f, 0.0f};

    // A-frag source: row = rowbase + mt*16 + l15, k = kc*KPER + kb*32 + lg*8
    const float* xr = x + (size_t)(rowbase + l15) * KDIM + kc * KPER + lg * 8;

#pragma unroll 1
    for (int kb = 0; kb < NKB; ++kb) {
        const float* xk = xr + kb * 32;
        f4 r0[4], r1[4];
#pragma unroll
        for (int mt = 0; mt < 4; ++mt) {
            const float* p = xk + (size_t)mt * 16 * KDIM;
            r0[mt] = *(const f4*)(p);
            r1[mt] = *(const f4*)(p + 4);
        }

        const int kbg  = kc * NKB + kb;
        const int bidx = (kbg * 2) * 64 + lane;
        const bf16x8 Bh0 = as_bf16x8(whi[bidx]);
        const bf16x8 Bl0 = as_bf16x8(wlo[bidx]);
        const bf16x8 Bh1 = as_bf16x8(whi[bidx + 64]);
        const bf16x8 Bl1 = as_bf16x8(wlo[bidx + 64]);

#pragma unroll
        for (int mt = 0; mt < 4; ++mt) {
            u32x4 ah, al;
            uint2 s0 = split_pair(r0[mt].x, r0[mt].y);
            uint2 s1 = split_pair(r0[mt].z, r0[mt].w);
            uint2 s2 = split_pair(r1[mt].x, r1[mt].y);
            uint2 s3 = split_pair(r1[mt].z, r1[mt].w);
            ah.x = s0.x; al.x = s0.y;
            ah.y = s1.x; al.y = s1.y;
            ah.z = s2.x; al.z = s2.y;
            ah.w = s3.x; al.w = s3.y;
            const bf16x8 Ah = as_bf16x8(ah);
            const bf16x8 Al = as_bf16x8(al);

            ss[mt] = fmaf(r0[mt].x, r0[mt].x, ss[mt]);
            ss[mt] = fmaf(r0[mt].y, r0[mt].y, ss[mt]);
            ss[mt] = fmaf(r0[mt].z, r0[mt].z, ss[mt]);
            ss[mt] = fmaf(r0[mt].w, r0[mt].w, ss[mt]);
            ss[mt] = fmaf(r1[mt].x, r1[mt].x, ss[mt]);
            ss[mt] = fmaf(r1[mt].y, r1[mt].y, ss[mt]);
            ss[mt] = fmaf(r1[mt].z, r1[mt].z, ss[mt]);
            ss[mt] = fmaf(r1[mt].w, r1[mt].w, ss[mt]);

            acc[mt][0] = __builtin_amdgcn_mfma_f32_16x16x32_bf16(Ah, Bh0, acc[mt][0], 0, 0, 0);
            acc[mt][1] = __builtin_amdgcn_mfma_f32_16x16x32_bf16(Ah, Bh1, acc[mt][1], 0, 0, 0);
            acc[mt][0] = __builtin_amdgcn_mfma_f32_16x16x32_bf16(Al, Bh0, acc[mt][0], 0, 0, 0);
            acc[mt][1] = __builtin_amdgcn_mfma_f32_16x16x32_bf16(Al, Bh1, acc[mt][1], 0, 0, 0);
            acc[mt][0] = __builtin_amdgcn_mfma_f32_16x16x32_bf16(Ah, Bl0, acc[mt][0], 0, 0, 0);
            acc[mt][1] = __builtin_amdgcn_mfma_f32_16x16x32_bf16(Ah, Bl1, acc[mt][1], 0, 0, 0);
        }
    }

    float* hc = hacc + (size_t)kc * NSLOT * TROWS;

    // sumsq: lanes {r, r+16, r+32, r+48} hold row r partials -> xor reduce
#pragma unroll
    for (int mt = 0; mt < 4; ++mt) {
        ss[mt] += __shfl_xor(ss[mt], 16);
        ss[mt] += __shfl_xor(ss[mt], 32);
    }
    const float ssel = (lg == 0) ? ss[0] : (lg == 1) ? ss[1] : (lg == 2) ? ss[2] : ss[3];
    hc[(size_t)NOUT * TROWS + rowbase + lane] = ssel;   // row = rowbase+lane

    // C frags: D col = lane&15, row = (lane>>4)*4 + reg -> one f4 store each
#pragma unroll
    for (int mt = 0; mt < 4; ++mt) {
        const int rowb = rowbase + mt * 16 + lg * 4;
        *(f4*)(hc + (size_t)l15 * TROWS + rowb) = acc[mt][0];
        if (l15 < 8)
            *(f4*)(hc + (size_t)(16 + l15) * TROWS + rowb) = acc[mt][1];
    }
}

// ---- collapse 64 split-K chunks: hfin[j][row] = sum_kc hacc[kc][j][row] ----
__global__ __launch_bounds__(256) void reduce_chunks(const float* __restrict__ hacc,
                                                     float* __restrict__ hfin) {
    const int i = blockIdx.x * 256 + threadIdx.x;    // 0 .. 25*4096-1
    float s = 0.0f;
#pragma unroll 1
    for (int c = 0; c < KC; ++c) s += hacc[(size_t)c * NSLOT * TROWS + i];
    hfin[i] = s;
}

__global__ __launch_bounds__(256) void sinkhorn_epilogue(const float* __restrict__ hfin,
                                                         const float* __restrict__ bias,
                                                         const float* __restrict__ alpha,
                                                         float* __restrict__ out) {
    const int row = blockIdx.x * 256 + threadIdx.x;

    float h[25];
#pragma unroll
    for (int j = 0; j < 25; ++j) h[j] = hfin[(size_t)j * TROWS + row];

    const float r_inv = fast_rsqrt(h[24] * (1.0f / (float)KDIM));
    const float a0 = alpha[0], a1 = alpha[1], a2 = alpha[2];

#pragma unroll
    for (int i = 0; i < 4; ++i) {
        const float zpre = fmaf(r_inv * a0, h[i], bias[i]);
        out[(size_t)row * 4 + i] = fast_rcp(1.0f + __expf(-zpre));
        const float zpo = fmaf(r_inv * a1, h[4 + i], bias[4 + i]);
        out[(size_t)16384 + (size_t)row * 4 + i] = 2.0f * fast_rcp(1.0f + __expf(-zpo));
    }

    float E[16];
#pragma unroll
    for (int q = 0; q < 16; ++q)
        E[q] = __expf(fmaf(r_inv * a2, h[8 + q], bias[8 + q]));

    float u0 = 1.0f, u1 = 1.0f, u2 = 1.0f, u3 = 1.0f;
    float v0 = 1.0f, v1 = 1.0f, v2 = 1.0f, v3 = 1.0f;
    float pu0 = 1.0f, pu1 = 1.0f, pu2 = 1.0f, pu3 = 1.0f;
    float pv0 = 1.0f, pv1 = 1.0f, pv2 = 1.0f, pv3 = 1.0f;

    // Bitwise fixed-point early exit (exact-output preserving; verified in
    // three passing rounds). Falls back to the full 400 if never triggered.
#pragma unroll 1
    for (int it = 0; it < 400; ++it) {
        float s0 = fmaf(E[0],  v0, E[1]  * v1) + fmaf(E[2],  v2, E[3]  * v3);
        float s1 = fmaf(E[4],  v0, E[5]  * v1) + fmaf(E[6],  v2, E[7]  * v3);
        float s2 = fmaf(E[8],  v0, E[9]  * v1) + fmaf(E[10], v2, E[11] * v3);
        float s3 = fmaf(E[12], v0, E[13] * v1) + fmaf(E[14], v2, E[15] * v3);
        u0 = fast_rcp(s0 + 1e-12f);
        u1 = fast_rcp(s1 + 1e-12f);
        u2 = fast_rcp(s2 + 1e-12f);
        u3 = fast_rcp(s3 + 1e-12f);
        float t0 = fmaf(E[0], u0, E[4]  * u1) + fmaf(E[8],  u2, E[12] * u3);
        float t1 = fmaf(E[1], u0, E[5]  * u1) + fmaf(E[9],  u2, E[13] * u3);
        float t2 = fmaf(E[2], u0, E[6]  * u1) + fmaf(E[10], u2, E[14] * u3);
        float t3 = fmaf(E[3], u0, E[7]  * u1) + fmaf(E[11], u2, E[15] * u3);
        v0 = fast_rcp(t0 + 1e-12f);
        v1 = fast_rcp(t1 + 1e-12f);
        v2 = fast_rcp(t2 + 1e-12f);
        v3 = fast_rcp(t3 + 1e-12f);

        const int conv = (u0 == pu0) & (u1 == pu1) & (u2 == pu2) & (u3 == pu3)
                       & (v0 == pv0) & (v1 == pv1) & (v2 == pv2) & (v3 == pv3);
        pu0 = u0; pu1 = u1; pu2 = u2; pu3 = u3;
        pv0 = v0; pv1 = v1; pv2 = v2; pv3 = v3;
        if (__all(conv)) break;
    }

    const size_t ob = 32768 + (size_t)row * 16;
    out[ob + 0]  = u0 * E[0]  * v0;
    out[ob + 1]  = u0 * E[1]  * v1;
    out[ob + 2]  = u0 * E[2]  * v2;
    out[ob + 3]  = u0 * E[3]  * v3;
    out[ob + 4]  = u1 * E[4]  * v0;
    out[ob + 5]  = u1 * E[5]  * v1;
    out[ob + 6]  = u1 * E[6]  * v2;
    out[ob + 7]  = u1 * E[7]  * v3;
    out[ob + 8]  = u2 * E[8]  * v0;
    out[ob + 9]  = u2 * E[9]  * v1;
    out[ob + 10] = u2 * E[10] * v2;
    out[ob + 11] = u2 * E[11] * v3;
    out[ob + 12] = u3 * E[12] * v0;
    out[ob + 13] = u3 * E[13] * v1;
    out[ob + 14] = u3 * E[14] * v2;
    out[ob + 15] = u3 * E[15] * v3;
}

extern "C" void kernel_launch(void* const* d_in, const int* in_sizes, int n_in,
                              void* d_out, int out_size, void* d_ws, size_t ws_size,
                              hipStream_t stream) {
    const float* x     = (const float*)d_in[0];
    const float* w     = (const float*)d_in[1];
    const float* bias  = (const float*)d_in[2];
    const float* alpha = (const float*)d_in[3];
    float* out = (float*)d_out;

    // workspace: [whi 1MB][wlo 1MB][hacc 26.2MB][hfin 0.4MB]
    u32x4* whi  = (u32x4*)d_ws;
    u32x4* wlo  = whi + NKBG * 2 * 64;
    float* hacc = (float*)d_ws + (size_t)2 * NKBG * 2 * 64 * 4;
    float* hfin = hacc + HACCF;

    make_wfrags<<<dim3(NKBG * 2 * 64 / 256), dim3(256), 0, stream>>>(w, whi, wlo);
    gemv_mfma<<<dim3(16 * KC), dim3(256), 0, stream>>>(x, whi, wlo, hacc);
    reduce_chunks<<<dim3(NSLOT * TROWS / 256), dim3(256), 0, stream>>>(hacc, hfin);
    sinkhorn_epilogue<<<dim3(TROWS / 256), dim3(256), 0, stream>>>(hfin, bias, alpha, out);
}